// Round 1
// baseline (851.587 us; speedup 1.0000x reference)
//
#include <hip/hip_runtime.h>
#include <hip/hip_fp16.h>

#define NN 50000
#define NE 800000
#define DEPTH 4
#define EPSF 1e-5f

typedef _Float16 f16;
typedef _Float16 f16x8 __attribute__((ext_vector_type(8)));
typedef float f32x4 __attribute__((ext_vector_type(4)));

#define MFMA16(a, b, c) __builtin_amdgcn_mfma_f32_16x16x32_f16(a, b, c, 0, 0, 0)

static __device__ __forceinline__ float silu_f(float x) {
    float e = __builtin_amdgcn_exp2f(x * -1.44269504088896f);
    return x * __builtin_amdgcn_rcpf(1.0f + e);
}

// ---------- weight convert+transpose: [D][K][C] f32 -> [D][C][K] f16 ----------
__global__ void k_wt(const float* __restrict__ src, f16* __restrict__ dst,
                     int K, int C, int total) {
    int i = blockIdx.x * 256 + threadIdx.x;
    if (i >= total) return;
    int kc = K * C;
    int d = i / kc, r = i - d * kc;
    int k = r / C, c = r - k * C;
    dst[d * kc + c * K + k] = (f16)src[i];
}

// ---------- h0 = silu(x @ nodeW + b) ----------
__global__ void k_init_h(const float* __restrict__ x, const float* __restrict__ nW,
                         const float* __restrict__ nb,
                         float* __restrict__ h32, f16* __restrict__ h16) {
    int i = blockIdx.x * 256 + threadIdx.x;
    if (i >= NN * 64) return;
    int n = i >> 6, u = i & 63;
    float v = silu_f(fmaf(x[2 * n], nW[u], fmaf(x[2 * n + 1], nW[64 + u], nb[u])));
    h32[i] = v;
    h16[i] = (f16)v;
}

// ---------- in-degree count ----------
__global__ void k_deg(const int* __restrict__ ei, float* __restrict__ deg) {
    int j = blockIdx.x * 256 + threadIdx.x;
    if (j < NE) unsafeAtomicAdd(&deg[ei[NE + j]], 1.0f);
}

// ---------- edge kernel: S[dst] += silu(cat[h_src, e] @ W1 + b1) ----------
// block = 256 (4 waves), each wave: 10 tiles of 16 edges -> 640 edges/block
#define EK_TPW 10
#define EK_EPB 640

__global__ __launch_bounds__(256, 2)
void k_edge(const int* __restrict__ ei, const float* __restrict__ ea,
            const f16* __restrict__ h16,
            const f16* __restrict__ w1t,   // this layer, [64][128] (c-major)
            const float* __restrict__ b1,
            const float* __restrict__ eW, const float* __restrict__ eb,
            float* __restrict__ S) {
    __shared__ f16 w1s[64 * 128];
    __shared__ float b1s[64], ews[64], ebs[64];

    int tid = threadIdx.x;
    for (int i = tid; i < 8192; i += 256) {
        int c = i >> 7, k = i & 127;
        w1s[(c << 7) | (k ^ ((c & 7) << 3))] = w1t[i];   // XOR-swizzled store
    }
    if (tid < 64) { b1s[tid] = b1[tid]; ews[tid] = eW[tid]; ebs[tid] = eb[tid]; }
    __syncthreads();

    int w = tid >> 6, lane = tid & 63;
    int row = lane & 15, g4 = lane >> 4;

    // hoist all 16 B-fragments of W1 (invariant across tiles)
    f16x8 bf[4][4];
    #pragma unroll
    for (int cb = 0; cb < 4; ++cb) {
        int c = row + 16 * cb;
        #pragma unroll
        for (int kb = 0; kb < 4; ++kb) {
            int k0 = kb * 32 + g4 * 8;
            bf[cb][kb] = *(const f16x8*)&w1s[(c << 7) | (k0 ^ ((c & 7) << 3))];
        }
    }

    int bbase = blockIdx.x * EK_EPB;
    #pragma unroll 1
    for (int t = 0; t < EK_TPW; ++t) {
        int e0 = bbase + (t * 4 + w) * 16;
        int src = ei[e0 + row];
        float eav = ea[e0 + row];

        // A-fragments: k 0..63 = h[src], k 64..127 = e (recomputed from scalar)
        f16x8 a0 = *(const f16x8*)&h16[src * 64 + g4 * 8];
        f16x8 a1 = *(const f16x8*)&h16[src * 64 + 32 + g4 * 8];
        f16x8 a2, a3;
        #pragma unroll
        for (int j = 0; j < 8; ++j) {
            int u = g4 * 8 + j;
            a2[j] = (f16)silu_f(fmaf(eav, ews[u], ebs[u]));
            a3[j] = (f16)silu_f(fmaf(eav, ews[u + 32], ebs[u + 32]));
        }

        f32x4 acc[4];
        #pragma unroll
        for (int cb = 0; cb < 4; ++cb) {
            float bv = b1s[row + 16 * cb];
            acc[cb] = (f32x4){bv, bv, bv, bv};
            acc[cb] = MFMA16(a0, bf[cb][0], acc[cb]);
            acc[cb] = MFMA16(a1, bf[cb][1], acc[cb]);
            acc[cb] = MFMA16(a2, bf[cb][2], acc[cb]);
            acc[cb] = MFMA16(a3, bf[cb][3], acc[cb]);
        }

        int er = e0 + g4 * 4;
        int d0 = ei[NE + er], d1 = ei[NE + er + 1];
        int d2 = ei[NE + er + 2], d3 = ei[NE + er + 3];
        #pragma unroll
        for (int cb = 0; cb < 4; ++cb) {
            int col = row + 16 * cb;
            unsafeAtomicAdd(&S[d0 * 64 + col], silu_f(acc[cb][0]));
            unsafeAtomicAdd(&S[d1 * 64 + col], silu_f(acc[cb][1]));
            unsafeAtomicAdd(&S[d2 * 64 + col], silu_f(acc[cb][2]));
            unsafeAtomicAdd(&S[d3 * 64 + col], silu_f(acc[cb][3]));
        }
    }
}

// ---------- node kernel: aggr=(S/deg)@W2+b2, update MLP, residual, LN ----------
#define NK_TPW 4
#define NK_TILES 3125

__global__ __launch_bounds__(256, 2)
void k_node(const f16* __restrict__ h16, const float* __restrict__ h32,
            const float* __restrict__ S, const float* __restrict__ deg,
            const f16* __restrict__ w2t, const float* __restrict__ b2,
            const f16* __restrict__ u1t, const float* __restrict__ b1u,
            const f16* __restrict__ u2t, const float* __restrict__ b2u,
            const float* __restrict__ lng, const float* __restrict__ lnb,
            float* __restrict__ h32o, f16* __restrict__ h16o) {
    __shared__ f16 u1s[64 * 128];
    __shared__ f16 w2s[64 * 64], u2s[64 * 64];
    __shared__ float b2s[64], b1us[64], b2us[64], lngs[64], lnbs[64];
    __shared__ f16 trs[4][16 * 64];

    int tid = threadIdx.x;
    for (int i = tid; i < 8192; i += 256) {
        int c = i >> 7, k = i & 127;
        u1s[(c << 7) | (k ^ ((c & 7) << 3))] = u1t[i];
    }
    for (int i = tid; i < 4096; i += 256) {
        int c = i >> 6, k = i & 63;
        int p = (c << 6) | (k ^ ((c & 7) << 3));
        w2s[p] = w2t[i];
        u2s[p] = u2t[i];
    }
    if (tid < 64) {
        b2s[tid] = b2[tid]; b1us[tid] = b1u[tid]; b2us[tid] = b2u[tid];
        lngs[tid] = lng[tid]; lnbs[tid] = lnb[tid];
    }
    __syncthreads();

    int w = tid >> 6, lane = tid & 63;
    int row = lane & 15, g4 = lane >> 4;
    f16* tp = trs[w];

    #pragma unroll 1
    for (int t = 0; t < NK_TPW; ++t) {
        int tile = (blockIdx.x * 4 + w) * NK_TPW + t;
        if (tile >= NK_TILES) continue;
        int n0 = tile * 16;
        int nA = n0 + row;

        // ---- aggr = (S/deg) @ W2 + b2*(deg>0) ----
        float rdA = __builtin_amdgcn_rcpf(fmaxf(deg[nA], 1.0f));
        const float* Srow = S + nA * 64;
        f16x8 sa0, sa1;
        #pragma unroll
        for (int j = 0; j < 8; ++j) {
            sa0[j] = (f16)(Srow[g4 * 8 + j] * rdA);
            sa1[j] = (f16)(Srow[32 + g4 * 8 + j] * rdA);
        }
        int nC = n0 + g4 * 4;
        float f0 = deg[nC] > 0.5f ? 1.f : 0.f;
        float f1 = deg[nC + 1] > 0.5f ? 1.f : 0.f;
        float f2 = deg[nC + 2] > 0.5f ? 1.f : 0.f;
        float f3 = deg[nC + 3] > 0.5f ? 1.f : 0.f;

        f32x4 agg[4];
        #pragma unroll
        for (int cb = 0; cb < 4; ++cb) {
            int c = row + 16 * cb;
            float bv = b2s[c];
            agg[cb] = (f32x4){bv * f0, bv * f1, bv * f2, bv * f3};
            f16x8 wb0 = *(const f16x8*)&w2s[(c << 6) | ((g4 * 8) ^ ((c & 7) << 3))];
            f16x8 wb1 = *(const f16x8*)&w2s[(c << 6) | ((32 + g4 * 8) ^ ((c & 7) << 3))];
            agg[cb] = MFMA16(sa0, wb0, agg[cb]);
            agg[cb] = MFMA16(sa1, wb1, agg[cb]);
        }

        // ---- transpose aggr (C-frag) -> A-frag via wave-private LDS ----
        #pragma unroll
        for (int cb = 0; cb < 4; ++cb) {
            int c = row + 16 * cb;
            #pragma unroll
            for (int v = 0; v < 4; ++v) {
                int r = g4 * 4 + v;
                tp[(r << 6) | (c ^ ((r & 7) << 3))] = (f16)agg[cb][v];
            }
        }
        f16x8 ha0 = *(const f16x8*)&h16[nA * 64 + g4 * 8];
        f16x8 ha1 = *(const f16x8*)&h16[nA * 64 + 32 + g4 * 8];
        f16x8 aa2 = *(const f16x8*)&tp[(row << 6) | ((g4 * 8) ^ ((row & 7) << 3))];
        f16x8 aa3 = *(const f16x8*)&tp[(row << 6) | ((32 + g4 * 8) ^ ((row & 7) << 3))];

        // ---- hid = silu(cat[h, aggr] @ U1 + b1u) ----
        f32x4 hid[4];
        #pragma unroll
        for (int cb = 0; cb < 4; ++cb) {
            int c = row + 16 * cb;
            float bv = b1us[c];
            hid[cb] = (f32x4){bv, bv, bv, bv};
            hid[cb] = MFMA16(ha0, *(const f16x8*)&u1s[(c << 7) | ((g4 * 8) ^ ((c & 7) << 3))], hid[cb]);
            hid[cb] = MFMA16(ha1, *(const f16x8*)&u1s[(c << 7) | ((32 + g4 * 8) ^ ((c & 7) << 3))], hid[cb]);
            hid[cb] = MFMA16(aa2, *(const f16x8*)&u1s[(c << 7) | ((64 + g4 * 8) ^ ((c & 7) << 3))], hid[cb]);
            hid[cb] = MFMA16(aa3, *(const f16x8*)&u1s[(c << 7) | ((96 + g4 * 8) ^ ((c & 7) << 3))], hid[cb]);
        }

        // silu -> LDS (reuse tp) -> A-frags
        #pragma unroll
        for (int cb = 0; cb < 4; ++cb) {
            int c = row + 16 * cb;
            #pragma unroll
            for (int v = 0; v < 4; ++v) {
                int r = g4 * 4 + v;
                tp[(r << 6) | (c ^ ((r & 7) << 3))] = (f16)silu_f(hid[cb][v]);
            }
        }
        f16x8 za0 = *(const f16x8*)&tp[(row << 6) | ((g4 * 8) ^ ((row & 7) << 3))];
        f16x8 za1 = *(const f16x8*)&tp[(row << 6) | ((32 + g4 * 8) ^ ((row & 7) << 3))];

        f32x4 out[4];
        #pragma unroll
        for (int cb = 0; cb < 4; ++cb) {
            int c = row + 16 * cb;
            float bv = b2us[c];
            out[cb] = (f32x4){bv, bv, bv, bv};
            out[cb] = MFMA16(za0, *(const f16x8*)&u2s[(c << 6) | ((g4 * 8) ^ ((c & 7) << 3))], out[cb]);
            out[cb] = MFMA16(za1, *(const f16x8*)&u2s[(c << 6) | ((32 + g4 * 8) ^ ((c & 7) << 3))], out[cb]);
        }

        // ---- residual + LayerNorm ----
        #pragma unroll
        for (int v = 0; v < 4; ++v) {
            int n = nC + v;
            float hp[4];
            float s = 0.f, q = 0.f;
            #pragma unroll
            for (int cb = 0; cb < 4; ++cb) {
                float xv = h32[n * 64 + row + 16 * cb] + out[cb][v];
                hp[cb] = xv; s += xv; q += xv * xv;
            }
            #pragma unroll
            for (int off = 1; off < 16; off <<= 1) {
                s += __shfl_xor(s, off, 64);
                q += __shfl_xor(q, off, 64);
            }
            float mu = s * 0.015625f;
            float var = q * 0.015625f - mu * mu;
            float rstd = __builtin_amdgcn_rsqf(var + EPSF);
            #pragma unroll
            for (int cb = 0; cb < 4; ++cb) {
                int c = row + 16 * cb;
                float o = (hp[cb] - mu) * rstd * lngs[c] + lnbs[c];
                h32o[n * 64 + c] = o;
                h16o[n * 64 + c] = (f16)o;
            }
        }
    }
}

extern "C" void kernel_launch(void* const* d_in, const int* in_sizes, int n_in,
                              void* d_out, int out_size, void* d_ws, size_t ws_size,
                              hipStream_t stream) {
    const float* x   = (const float*)d_in[0];
    const int*   ei  = (const int*)d_in[1];
    const float* ea  = (const float*)d_in[2];
    const float* nW  = (const float*)d_in[3];
    const float* nb  = (const float*)d_in[4];
    const float* eW  = (const float*)d_in[5];
    const float* eb  = (const float*)d_in[6];
    const float* mW1 = (const float*)d_in[7];
    const float* mb1 = (const float*)d_in[8];
    const float* mW2 = (const float*)d_in[9];
    const float* mb2 = (const float*)d_in[10];
    const float* uW1 = (const float*)d_in[11];
    const float* ub1 = (const float*)d_in[12];
    const float* uW2 = (const float*)d_in[13];
    const float* ub2 = (const float*)d_in[14];
    const float* lng = (const float*)d_in[15];
    const float* lnb = (const float*)d_in[16];

    char* p = (char*)d_ws;
    float* S   = (float*)p;  p += (size_t)NN * 64 * 4;
    float* h32 = (float*)p;  p += (size_t)NN * 64 * 4;
    f16*   h16 = (f16*)p;    p += (size_t)NN * 64 * 2;
    float* deg = (float*)p;  p += (size_t)NN * 4;
    f16*   w1t = (f16*)p;    p += (size_t)DEPTH * 8192 * 2;
    f16*   w2t = (f16*)p;    p += (size_t)DEPTH * 4096 * 2;
    f16*   u1t = (f16*)p;    p += (size_t)DEPTH * 8192 * 2;
    f16*   u2t = (f16*)p;    p += (size_t)DEPTH * 4096 * 2;

    k_wt<<<(DEPTH * 8192 + 255) / 256, 256, 0, stream>>>(mW1, w1t, 128, 64, DEPTH * 8192);
    k_wt<<<(DEPTH * 4096 + 255) / 256, 256, 0, stream>>>(mW2, w2t, 64, 64, DEPTH * 4096);
    k_wt<<<(DEPTH * 8192 + 255) / 256, 256, 0, stream>>>(uW1, u1t, 128, 64, DEPTH * 8192);
    k_wt<<<(DEPTH * 4096 + 255) / 256, 256, 0, stream>>>(uW2, u2t, 64, 64, DEPTH * 4096);
    k_init_h<<<(NN * 64 + 255) / 256, 256, 0, stream>>>(x, nW, nb, h32, h16);
    hipMemsetAsync(deg, 0, (size_t)NN * 4, stream);
    k_deg<<<(NE + 255) / 256, 256, 0, stream>>>(ei, deg);

    for (int l = 0; l < DEPTH; ++l) {
        hipMemsetAsync(S, 0, (size_t)NN * 64 * 4, stream);
        k_edge<<<NE / EK_EPB, 256, 0, stream>>>(ei, ea, h16,
            w1t + (size_t)l * 8192, mb1 + l * 64, eW, eb, S);
        k_node<<<196, 256, 0, stream>>>(h16, h32, S, deg,
            w2t + (size_t)l * 4096, mb2 + l * 64,
            u1t + (size_t)l * 8192, ub1 + l * 64,
            u2t + (size_t)l * 4096, ub2 + l * 64,
            lng + l * 64, lnb + l * 64,
            (l == DEPTH - 1) ? (float*)d_out : h32, h16);
    }
}

// Round 2
// 825.350 us; speedup vs baseline: 1.0318x; 1.0318x over previous
//
#include <hip/hip_runtime.h>
#include <hip/hip_fp16.h>

#define NN 50000
#define NE 800000
#define DEPTH 4
#define EPSF 1e-5f

typedef _Float16 f16;
typedef _Float16 f16x8 __attribute__((ext_vector_type(8)));
typedef float f32x4 __attribute__((ext_vector_type(4)));

#define MFMA16(a, b, c) __builtin_amdgcn_mfma_f32_16x16x32_f16(a, b, c, 0, 0, 0)

static __device__ __forceinline__ float silu_f(float x) {
    float e = __builtin_amdgcn_exp2f(x * -1.44269504088896f);
    return x * __builtin_amdgcn_rcpf(1.0f + e);
}

// ---------- weight convert+transpose: [D][K][C] f32 -> [D][C][K] f16 ----------
__global__ void k_wt(const float* __restrict__ src, f16* __restrict__ dst,
                     int K, int C, int total) {
    int i = blockIdx.x * 256 + threadIdx.x;
    if (i >= total) return;
    int kc = K * C;
    int d = i / kc, r = i - d * kc;
    int k = r / C, c = r - k * C;
    dst[d * kc + c * K + k] = (f16)src[i];
}

// ---------- h0 = silu(x @ nodeW + b) ----------
__global__ void k_init_h(const float* __restrict__ x, const float* __restrict__ nW,
                         const float* __restrict__ nb,
                         float* __restrict__ h32, f16* __restrict__ h16) {
    int i = blockIdx.x * 256 + threadIdx.x;
    if (i >= NN * 64) return;
    int n = i >> 6, u = i & 63;
    float v = silu_f(fmaf(x[2 * n], nW[u], fmaf(x[2 * n + 1], nW[64 + u], nb[u])));
    h32[i] = v;
    h16[i] = (f16)v;
}

// ---------- in-degree count (int) ----------
__global__ void k_deg(const int* __restrict__ ei, int* __restrict__ cnt) {
    int j = blockIdx.x * 256 + threadIdx.x;
    if (j < NE) atomicAdd(&cnt[ei[NE + j]], 1);
}

// ---------- exclusive prefix scan over cnt -> rowptr, cursor (1 block) ----------
__global__ void k_scan(const int* __restrict__ cnt, int* __restrict__ rowptr,
                       int* __restrict__ cursor) {
    __shared__ int wsum[16];
    __shared__ int woff[16];
    __shared__ int btot;
    __shared__ int s_carry;
    int tid = threadIdx.x, lane = tid & 63, wid = tid >> 6;
    if (tid == 0) s_carry = 0;
    __syncthreads();
    for (int base = 0; base < NN; base += 1024) {
        int i = base + tid;
        int v = (i < NN) ? cnt[i] : 0;
        int incl = v;
        #pragma unroll
        for (int off = 1; off < 64; off <<= 1) {
            int t = __shfl_up(incl, off, 64);
            if (lane >= off) incl += t;
        }
        if (lane == 63) wsum[wid] = incl;
        __syncthreads();
        if (tid < 16) {
            int wv = wsum[lane];
            int wincl = wv;
            #pragma unroll
            for (int off = 1; off < 16; off <<= 1) {
                int t = __shfl_up(wincl, off, 64);
                if (lane >= off) wincl += t;
            }
            woff[lane] = wincl - wv;
            if (lane == 15) btot = wincl;
        }
        __syncthreads();
        int excl = incl - v + woff[wid] + s_carry;
        if (i < NN) { rowptr[i] = excl; cursor[i] = excl; }
        __syncthreads();
        if (tid == 0) s_carry += btot;
        __syncthreads();
    }
    if (threadIdx.x == 0) rowptr[NN] = s_carry;
}

// ---------- scatter edges into dst-sorted order ----------
__global__ void k_scatter(const int* __restrict__ ei, const float* __restrict__ ea,
                          int* __restrict__ cursor,
                          int* __restrict__ esrc, float* __restrict__ eavs) {
    int j = blockIdx.x * 256 + threadIdx.x;
    if (j >= NE) return;
    int d = ei[NE + j];
    int p = atomicAdd(&cursor[d], 1);
    esrc[p] = ei[j];
    eavs[p] = ea[j];
}

// ---------- edge kernel: S[n] = sum_{edges->n} silu(cat[h_src,e] @ W1 + b1) ----------
// persistent: 256 blocks x 8 waves; each wave owns NPW consecutive nodes.
#define EB_BLOCKS 256
#define EB_WAVES 8
#define NPW 25   // ceil(50000 / 2048)

__global__ __launch_bounds__(512, 4)
void k_edge(const int* __restrict__ rowptr, const int* __restrict__ esrc,
            const float* __restrict__ eavs,
            const f16* __restrict__ h16,
            const f16* __restrict__ w1t, const float* __restrict__ b1,
            const float* __restrict__ eW, const float* __restrict__ eb,
            float* __restrict__ S) {
    __shared__ f16 w1s[64 * 128];
    __shared__ float b1s[64], ews[64], ebs[64];

    int tid = threadIdx.x;
    for (int i = tid; i < 8192; i += 512) {
        int c = i >> 7, k = i & 127;
        w1s[(c << 7) | (k ^ ((c & 7) << 3))] = w1t[i];
    }
    if (tid < 64) { b1s[tid] = b1[tid]; ews[tid] = eW[tid]; ebs[tid] = eb[tid]; }
    __syncthreads();

    int w = tid >> 6, lane = tid & 63;
    int row = lane & 15, g4 = lane >> 4;

    // hoist all 16 B-fragments of W1 (invariant)
    f16x8 bf[4][4];
    #pragma unroll
    for (int cb = 0; cb < 4; ++cb) {
        int c = row + 16 * cb;
        #pragma unroll
        for (int kb = 0; kb < 4; ++kb) {
            int k0 = kb * 32 + g4 * 8;
            bf[cb][kb] = *(const f16x8*)&w1s[(c << 7) | (k0 ^ ((c & 7) << 3))];
        }
    }

    int gw = blockIdx.x * EB_WAVES + w;
    int nbeg = gw * NPW;
    int nend = nbeg + NPW; if (nend > NN) nend = NN;

    for (int n = nbeg; n < nend; ++n) {
        int kb0 = rowptr[n], ke = rowptr[n + 1];
        float tot0 = 0.f, tot1 = 0.f, tot2 = 0.f, tot3 = 0.f;

        for (int p0 = kb0; p0 < ke; p0 += 16) {
            int cntc = ke - p0;                 // valid rows this chunk (>=1)
            int pr = p0 + row;
            int prc = pr < ke ? pr : ke - 1;    // clamp padded rows
            int src = esrc[prc];
            float ev = eavs[prc];

            f16x8 a0 = *(const f16x8*)&h16[src * 64 + g4 * 8];
            f16x8 a1 = *(const f16x8*)&h16[src * 64 + 32 + g4 * 8];
            f16x8 a2, a3;
            #pragma unroll
            for (int j = 0; j < 8; ++j) {
                int u = g4 * 8 + j;
                a2[j] = (f16)silu_f(fmaf(ev, ews[u], ebs[u]));
                a3[j] = (f16)silu_f(fmaf(ev, ews[u + 32], ebs[u + 32]));
            }

            #pragma unroll
            for (int cb = 0; cb < 4; ++cb) {
                float bv = b1s[row + 16 * cb];
                f32x4 acc = (f32x4){bv, bv, bv, bv};
                acc = MFMA16(a0, bf[cb][0], acc);
                acc = MFMA16(a1, bf[cb][1], acc);
                acc = MFMA16(a2, bf[cb][2], acc);
                acc = MFMA16(a3, bf[cb][3], acc);
                float s = 0.f;
                #pragma unroll
                for (int v = 0; v < 4; ++v)
                    if (g4 * 4 + v < cntc) s += silu_f(acc[v]);
                if (cb == 0) tot0 += s;
                else if (cb == 1) tot1 += s;
                else if (cb == 2) tot2 += s;
                else tot3 += s;
            }
        }

        // reduce across the 4 row-groups (g4)
        tot0 += __shfl_xor(tot0, 16, 64); tot0 += __shfl_xor(tot0, 32, 64);
        tot1 += __shfl_xor(tot1, 16, 64); tot1 += __shfl_xor(tot1, 32, 64);
        tot2 += __shfl_xor(tot2, 16, 64); tot2 += __shfl_xor(tot2, 32, 64);
        tot3 += __shfl_xor(tot3, 16, 64); tot3 += __shfl_xor(tot3, 32, 64);

        // redistribute so lane l holds col l, then one coalesced 256B store
        float t0 = __shfl(tot0, lane & 15, 64);
        float t1 = __shfl(tot1, lane & 15, 64);
        float t2 = __shfl(tot2, lane & 15, 64);
        float t3 = __shfl(tot3, lane & 15, 64);
        float outv = (lane < 16) ? t0 : (lane < 32) ? t1 : (lane < 48) ? t2 : t3;
        S[n * 64 + lane] = outv;
    }
}

// ---------- node kernel: aggr=(S/deg)@W2+b2, update MLP, residual, LN ----------
#define NK_TILES 3125

__global__ __launch_bounds__(256, 2)
void k_node(const f16* __restrict__ h16, const float* __restrict__ h32,
            const float* __restrict__ S, const int* __restrict__ rowptr,
            const f16* __restrict__ w2t, const float* __restrict__ b2,
            const f16* __restrict__ u1t, const float* __restrict__ b1u,
            const f16* __restrict__ u2t, const float* __restrict__ b2u,
            const float* __restrict__ lng, const float* __restrict__ lnb,
            float* __restrict__ h32o, f16* __restrict__ h16o) {
    __shared__ f16 u1s[64 * 128];
    __shared__ f16 w2s[64 * 64], u2s[64 * 64];
    __shared__ float b2s[64], b1us[64], b2us[64], lngs[64], lnbs[64];
    __shared__ f16 trs[4][16 * 64];

    int tid = threadIdx.x;
    for (int i = tid; i < 8192; i += 256) {
        int c = i >> 7, k = i & 127;
        u1s[(c << 7) | (k ^ ((c & 7) << 3))] = u1t[i];
    }
    for (int i = tid; i < 4096; i += 256) {
        int c = i >> 6, k = i & 63;
        int p = (c << 6) | (k ^ ((c & 7) << 3));
        w2s[p] = w2t[i];
        u2s[p] = u2t[i];
    }
    if (tid < 64) {
        b2s[tid] = b2[tid]; b1us[tid] = b1u[tid]; b2us[tid] = b2u[tid];
        lngs[tid] = lng[tid]; lnbs[tid] = lnb[tid];
    }
    __syncthreads();

    int w = tid >> 6, lane = tid & 63;
    int row = lane & 15, g4 = lane >> 4;
    f16* tp = trs[w];

    int tile = blockIdx.x * 4 + w;
    if (tile >= NK_TILES) return;
    int n0 = tile * 16;
    int nA = n0 + row;

    // ---- aggr = (S/deg) @ W2 + b2*(deg>0) ----
    int degA = rowptr[nA + 1] - rowptr[nA];
    float rdA = __builtin_amdgcn_rcpf((float)(degA > 0 ? degA : 1));
    const float* Srow = S + nA * 64;
    f16x8 sa0, sa1;
    #pragma unroll
    for (int j = 0; j < 8; ++j) {
        sa0[j] = (f16)(Srow[g4 * 8 + j] * rdA);
        sa1[j] = (f16)(Srow[32 + g4 * 8 + j] * rdA);
    }
    int nC = n0 + g4 * 4;
    int r0 = rowptr[nC], r1 = rowptr[nC + 1], r2 = rowptr[nC + 2],
        r3 = rowptr[nC + 3], r4 = rowptr[nC + 4];
    float f0 = r1 > r0 ? 1.f : 0.f;
    float f1 = r2 > r1 ? 1.f : 0.f;
    float f2 = r3 > r2 ? 1.f : 0.f;
    float f3 = r4 > r3 ? 1.f : 0.f;

    f32x4 agg[4];
    #pragma unroll
    for (int cb = 0; cb < 4; ++cb) {
        int c = row + 16 * cb;
        float bv = b2s[c];
        agg[cb] = (f32x4){bv * f0, bv * f1, bv * f2, bv * f3};
        f16x8 wb0 = *(const f16x8*)&w2s[(c << 6) | ((g4 * 8) ^ ((c & 7) << 3))];
        f16x8 wb1 = *(const f16x8*)&w2s[(c << 6) | ((32 + g4 * 8) ^ ((c & 7) << 3))];
        agg[cb] = MFMA16(sa0, wb0, agg[cb]);
        agg[cb] = MFMA16(sa1, wb1, agg[cb]);
    }

    // ---- transpose aggr (C-frag) -> A-frag via wave-private LDS ----
    #pragma unroll
    for (int cb = 0; cb < 4; ++cb) {
        int c = row + 16 * cb;
        #pragma unroll
        for (int v = 0; v < 4; ++v) {
            int r = g4 * 4 + v;
            tp[(r << 6) | (c ^ ((r & 7) << 3))] = (f16)agg[cb][v];
        }
    }
    f16x8 ha0 = *(const f16x8*)&h16[nA * 64 + g4 * 8];
    f16x8 ha1 = *(const f16x8*)&h16[nA * 64 + 32 + g4 * 8];
    f16x8 aa2 = *(const f16x8*)&tp[(row << 6) | ((g4 * 8) ^ ((row & 7) << 3))];
    f16x8 aa3 = *(const f16x8*)&tp[(row << 6) | ((32 + g4 * 8) ^ ((row & 7) << 3))];

    // ---- hid = silu(cat[h, aggr] @ U1 + b1u) ----
    f32x4 hid[4];
    #pragma unroll
    for (int cb = 0; cb < 4; ++cb) {
        int c = row + 16 * cb;
        float bv = b1us[c];
        hid[cb] = (f32x4){bv, bv, bv, bv};
        hid[cb] = MFMA16(ha0, *(const f16x8*)&u1s[(c << 7) | ((g4 * 8) ^ ((c & 7) << 3))], hid[cb]);
        hid[cb] = MFMA16(ha1, *(const f16x8*)&u1s[(c << 7) | ((32 + g4 * 8) ^ ((c & 7) << 3))], hid[cb]);
        hid[cb] = MFMA16(aa2, *(const f16x8*)&u1s[(c << 7) | ((64 + g4 * 8) ^ ((c & 7) << 3))], hid[cb]);
        hid[cb] = MFMA16(aa3, *(const f16x8*)&u1s[(c << 7) | ((96 + g4 * 8) ^ ((c & 7) << 3))], hid[cb]);
    }

    // silu -> LDS (reuse tp) -> A-frags
    __syncthreads();   // wave-private buffer, but re-sync cheap; actually wave-private: not needed. kept out.
    #pragma unroll
    for (int cb = 0; cb < 4; ++cb) {
        int c = row + 16 * cb;
        #pragma unroll
        for (int v = 0; v < 4; ++v) {
            int r = g4 * 4 + v;
            tp[(r << 6) | (c ^ ((r & 7) << 3))] = (f16)silu_f(hid[cb][v]);
        }
    }
    f16x8 za0 = *(const f16x8*)&tp[(row << 6) | ((g4 * 8) ^ ((row & 7) << 3))];
    f16x8 za1 = *(const f16x8*)&tp[(row << 6) | ((32 + g4 * 8) ^ ((row & 7) << 3))];

    f32x4 out[4];
    #pragma unroll
    for (int cb = 0; cb < 4; ++cb) {
        int c = row + 16 * cb;
        float bv = b2us[c];
        out[cb] = (f32x4){bv, bv, bv, bv};
        out[cb] = MFMA16(za0, *(const f16x8*)&u2s[(c << 6) | ((g4 * 8) ^ ((c & 7) << 3))], out[cb]);
        out[cb] = MFMA16(za1, *(const f16x8*)&u2s[(c << 6) | ((32 + g4 * 8) ^ ((c & 7) << 3))], out[cb]);
    }

    // ---- residual + LayerNorm ----
    #pragma unroll
    for (int v = 0; v < 4; ++v) {
        int n = nC + v;
        float hp[4];
        float s = 0.f, q = 0.f;
        #pragma unroll
        for (int cb = 0; cb < 4; ++cb) {
            float xv = h32[n * 64 + row + 16 * cb] + out[cb][v];
            hp[cb] = xv; s += xv; q += xv * xv;
        }
        #pragma unroll
        for (int off = 1; off < 16; off <<= 1) {
            s += __shfl_xor(s, off, 64);
            q += __shfl_xor(q, off, 64);
        }
        float mu = s * 0.015625f;
        float var = q * 0.015625f - mu * mu;
        float rstd = __builtin_amdgcn_rsqf(var + EPSF);
        #pragma unroll
        for (int cb = 0; cb < 4; ++cb) {
            int c = row + 16 * cb;
            float o = (hp[cb] - mu) * rstd * lngs[c] + lnbs[c];
            h32o[n * 64 + c] = o;
            h16o[n * 64 + c] = (f16)o;
        }
    }
}

extern "C" void kernel_launch(void* const* d_in, const int* in_sizes, int n_in,
                              void* d_out, int out_size, void* d_ws, size_t ws_size,
                              hipStream_t stream) {
    const float* x   = (const float*)d_in[0];
    const int*   ei  = (const int*)d_in[1];
    const float* ea  = (const float*)d_in[2];
    const float* nW  = (const float*)d_in[3];
    const float* nb  = (const float*)d_in[4];
    const float* eW  = (const float*)d_in[5];
    const float* eb  = (const float*)d_in[6];
    const float* mW1 = (const float*)d_in[7];
    const float* mb1 = (const float*)d_in[8];
    const float* mW2 = (const float*)d_in[9];
    const float* mb2 = (const float*)d_in[10];
    const float* uW1 = (const float*)d_in[11];
    const float* ub1 = (const float*)d_in[12];
    const float* uW2 = (const float*)d_in[13];
    const float* ub2 = (const float*)d_in[14];
    const float* lng = (const float*)d_in[15];
    const float* lnb = (const float*)d_in[16];

    char* p = (char*)d_ws;
    float* S    = (float*)p;  p += (size_t)NN * 64 * 4;
    float* h32  = (float*)p;  p += (size_t)NN * 64 * 4;
    f16*   h16  = (f16*)p;    p += (size_t)NN * 64 * 2;
    int*   rowptr = (int*)p;  p += (size_t)(NN + 1) * 4;
    int*   cursor = (int*)p;  p += (size_t)NN * 4;
    int*   cnt    = (int*)p;  p += (size_t)NN * 4;
    int*   esrc   = (int*)p;  p += (size_t)NE * 4;
    float* eavs   = (float*)p; p += (size_t)NE * 4;
    f16*   w1t = (f16*)p;    p += (size_t)DEPTH * 8192 * 2;
    f16*   w2t = (f16*)p;    p += (size_t)DEPTH * 4096 * 2;
    f16*   u1t = (f16*)p;    p += (size_t)DEPTH * 8192 * 2;
    f16*   u2t = (f16*)p;    p += (size_t)DEPTH * 4096 * 2;

    k_wt<<<(DEPTH * 8192 + 255) / 256, 256, 0, stream>>>(mW1, w1t, 128, 64, DEPTH * 8192);
    k_wt<<<(DEPTH * 4096 + 255) / 256, 256, 0, stream>>>(mW2, w2t, 64, 64, DEPTH * 4096);
    k_wt<<<(DEPTH * 8192 + 255) / 256, 256, 0, stream>>>(uW1, u1t, 128, 64, DEPTH * 8192);
    k_wt<<<(DEPTH * 4096 + 255) / 256, 256, 0, stream>>>(uW2, u2t, 64, 64, DEPTH * 4096);
    k_init_h<<<(NN * 64 + 255) / 256, 256, 0, stream>>>(x, nW, nb, h32, h16);

    hipMemsetAsync(cnt, 0, (size_t)NN * 4, stream);
    k_deg<<<(NE + 255) / 256, 256, 0, stream>>>(ei, cnt);
    k_scan<<<1, 1024, 0, stream>>>(cnt, rowptr, cursor);
    k_scatter<<<(NE + 255) / 256, 256, 0, stream>>>(ei, ea, cursor, esrc, eavs);

    for (int l = 0; l < DEPTH; ++l) {
        k_edge<<<EB_BLOCKS, 512, 0, stream>>>(rowptr, esrc, eavs, h16,
            w1t + (size_t)l * 8192, mb1 + l * 64, eW, eb, S);
        k_node<<<(NK_TILES + 3) / 4, 256, 0, stream>>>(h16, h32, S, rowptr,
            w2t + (size_t)l * 4096, mb2 + l * 64,
            u1t + (size_t)l * 8192, ub1 + l * 64,
            u2t + (size_t)l * 4096, ub2 + l * 64,
            lng + l * 64, lnb + l * 64,
            (l == DEPTH - 1) ? (float*)d_out : h32, h16);
    }
}

// Round 3
// 681.222 us; speedup vs baseline: 1.2501x; 1.2116x over previous
//
#include <hip/hip_runtime.h>
#include <hip/hip_fp16.h>

#define NN 50000
#define NE 800000
#define DEPTH 4
#define EPSF 1e-5f

typedef _Float16 f16;
typedef _Float16 f16x8 __attribute__((ext_vector_type(8)));
typedef float f32x4 __attribute__((ext_vector_type(4)));

#define MFMA16(a, b, c) __builtin_amdgcn_mfma_f32_16x16x32_f16(a, b, c, 0, 0, 0)

static __device__ __forceinline__ float silu_f(float x) {
    float e = __builtin_amdgcn_exp2f(x * -1.44269504088896f);
    return x * __builtin_amdgcn_rcpf(1.0f + e);
}

// ---------- weight convert+transpose: [D][K][C] f32 -> [D][C][K] f16 ----------
__global__ void k_wt(const float* __restrict__ src, f16* __restrict__ dst,
                     int K, int C, int total) {
    int i = blockIdx.x * 256 + threadIdx.x;
    if (i >= total) return;
    int kc = K * C;
    int d = i / kc, r = i - d * kc;
    int k = r / C, c = r - k * C;
    dst[d * kc + c * K + k] = (f16)src[i];
}

// ---------- h0 = silu(x @ nodeW + b) ----------
__global__ void k_init_h(const float* __restrict__ x, const float* __restrict__ nW,
                         const float* __restrict__ nb,
                         float* __restrict__ h32, f16* __restrict__ h16) {
    int i = blockIdx.x * 256 + threadIdx.x;
    if (i >= NN * 64) return;
    int n = i >> 6, u = i & 63;
    float v = silu_f(fmaf(x[2 * n], nW[u], fmaf(x[2 * n + 1], nW[64 + u], nb[u])));
    h32[i] = v;
    h16[i] = (f16)v;
}

// ---------- in-degree count (int) ----------
__global__ void k_deg(const int* __restrict__ ei, int* __restrict__ cnt) {
    int j = blockIdx.x * 256 + threadIdx.x;
    if (j < NE) atomicAdd(&cnt[ei[NE + j]], 1);
}

// ---------- exclusive prefix scan over cnt -> rowptr, cursor (1 block) ----------
__global__ void k_scan(const int* __restrict__ cnt, int* __restrict__ rowptr,
                       int* __restrict__ cursor) {
    __shared__ int wsum[16];
    __shared__ int woff[16];
    __shared__ int btot;
    __shared__ int s_carry;
    int tid = threadIdx.x, lane = tid & 63, wid = tid >> 6;
    if (tid == 0) s_carry = 0;
    __syncthreads();
    for (int base = 0; base < NN; base += 1024) {
        int i = base + tid;
        int v = (i < NN) ? cnt[i] : 0;
        int incl = v;
        #pragma unroll
        for (int off = 1; off < 64; off <<= 1) {
            int t = __shfl_up(incl, off, 64);
            if (lane >= off) incl += t;
        }
        if (lane == 63) wsum[wid] = incl;
        __syncthreads();
        if (tid < 16) {
            int wv = wsum[lane];
            int wincl = wv;
            #pragma unroll
            for (int off = 1; off < 16; off <<= 1) {
                int t = __shfl_up(wincl, off, 64);
                if (lane >= off) wincl += t;
            }
            woff[lane] = wincl - wv;
            if (lane == 15) btot = wincl;
        }
        __syncthreads();
        int excl = incl - v + woff[wid] + s_carry;
        if (i < NN) { rowptr[i] = excl; cursor[i] = excl; }
        __syncthreads();
        if (tid == 0) s_carry += btot;
        __syncthreads();
    }
    if (threadIdx.x == 0) rowptr[NN] = s_carry;
}

// ---------- scatter edges into dst-sorted order ----------
__global__ void k_scatter(const int* __restrict__ ei, const float* __restrict__ ea,
                          int* __restrict__ cursor,
                          int* __restrict__ esrc, float* __restrict__ eavs) {
    int j = blockIdx.x * 256 + threadIdx.x;
    if (j >= NE) return;
    int d = ei[NE + j];
    int p = atomicAdd(&cursor[d], 1);
    esrc[p] = ei[j];
    eavs[p] = ea[j];
}

// ---------- e16[p][u] = silu(eavs[p]*eW[u]+eb[u])  (layer-invariant) ----------
__global__ void k_e16(const float* __restrict__ eavs, const float* __restrict__ eW,
                      const float* __restrict__ eb, f16* __restrict__ e16) {
    int i = blockIdx.x * 256 + threadIdx.x;
    if (i >= NE * 64) return;
    int p = i >> 6, u = i & 63;
    e16[i] = (f16)silu_f(fmaf(eavs[p], eW[u], eb[u]));
}

// ---------- edge kernel: S[n] = sum_{edges->n} silu(cat[h_src,e] @ W1 + b1) ----------
// persistent: 894 blocks x 8 waves = 7152 waves; each wave owns NPW consecutive nodes.
#define EK_BLOCKS 894
#define NPW 7

template<bool USE_E16>
__global__ __launch_bounds__(512, 4)
void k_edge(const int* __restrict__ rowptr, const int* __restrict__ esrc,
            const float* __restrict__ eavs, const f16* __restrict__ e16,
            const f16* __restrict__ h16,
            const f16* __restrict__ w1t, const float* __restrict__ b1,
            const float* __restrict__ eW, const float* __restrict__ eb,
            float* __restrict__ S) {
    __shared__ f16 w1s[64 * 128];
    __shared__ float b1s[64], ews[64], ebs[64];

    int tid = threadIdx.x;
    for (int i = tid; i < 8192; i += 512) {
        int c = i >> 7, k = i & 127;
        w1s[(c << 7) | (k ^ ((c & 7) << 3))] = w1t[i];
    }
    if (tid < 64) { b1s[tid] = b1[tid]; ews[tid] = eW[tid]; ebs[tid] = eb[tid]; }
    __syncthreads();

    int w = tid >> 6, lane = tid & 63;
    int row = lane & 15, g4 = lane >> 4;

    int gw = blockIdx.x * 8 + w;
    int nbeg = gw * NPW;
    if (nbeg >= NN) return;
    int nend = nbeg + NPW; if (nend > NN) nend = NN;

    // B-fragments of W1 (layer-invariant within kernel); compiler may keep in
    // regs or re-read from LDS depending on pressure.
    f16x8 bf[4][4];
    #pragma unroll
    for (int cb = 0; cb < 4; ++cb) {
        int c = row + 16 * cb;
        #pragma unroll
        for (int kb = 0; kb < 4; ++kb) {
            int k0 = kb * 32 + g4 * 8;
            bf[cb][kb] = *(const f16x8*)&w1s[(c << 7) | (k0 ^ ((c & 7) << 3))];
        }
    }

    for (int n = nbeg; n < nend; ++n) {
        int kb0 = rowptr[n], ke = rowptr[n + 1];
        float tot0 = 0.f, tot1 = 0.f, tot2 = 0.f, tot3 = 0.f;

        if (ke > kb0) {
            int prc = kb0 + row; if (prc > ke - 1) prc = ke - 1;
            int src = esrc[prc];
            f16x8 a0 = *(const f16x8*)&h16[(size_t)src * 64 + g4 * 8];
            f16x8 a1 = *(const f16x8*)&h16[(size_t)src * 64 + 32 + g4 * 8];
            f16x8 a2, a3;
            if (USE_E16) {
                a2 = *(const f16x8*)&e16[(size_t)prc * 64 + g4 * 8];
                a3 = *(const f16x8*)&e16[(size_t)prc * 64 + 32 + g4 * 8];
            } else {
                float ev = eavs[prc];
                #pragma unroll
                for (int j = 0; j < 8; ++j) {
                    int u = g4 * 8 + j;
                    a2[j] = (f16)silu_f(fmaf(ev, ews[u], ebs[u]));
                    a3[j] = (f16)silu_f(fmaf(ev, ews[u + 32], ebs[u + 32]));
                }
            }

            for (int p0 = kb0; p0 < ke; p0 += 16) {
                int cntc = ke - p0;
                int np = p0 + 16;
                f16x8 na0, na1, na2, na3;
                if (np < ke) {             // wave-uniform prefetch of next chunk
                    int prn = np + row; if (prn > ke - 1) prn = ke - 1;
                    int srcn = esrc[prn];
                    na0 = *(const f16x8*)&h16[(size_t)srcn * 64 + g4 * 8];
                    na1 = *(const f16x8*)&h16[(size_t)srcn * 64 + 32 + g4 * 8];
                    if (USE_E16) {
                        na2 = *(const f16x8*)&e16[(size_t)prn * 64 + g4 * 8];
                        na3 = *(const f16x8*)&e16[(size_t)prn * 64 + 32 + g4 * 8];
                    } else {
                        float evn = eavs[prn];
                        #pragma unroll
                        for (int j = 0; j < 8; ++j) {
                            int u = g4 * 8 + j;
                            na2[j] = (f16)silu_f(fmaf(evn, ews[u], ebs[u]));
                            na3[j] = (f16)silu_f(fmaf(evn, ews[u + 32], ebs[u + 32]));
                        }
                    }
                }

                #pragma unroll
                for (int cb = 0; cb < 4; ++cb) {
                    float bv = b1s[row + 16 * cb];
                    f32x4 acc = (f32x4){bv, bv, bv, bv};
                    acc = MFMA16(a0, bf[cb][0], acc);
                    acc = MFMA16(a1, bf[cb][1], acc);
                    acc = MFMA16(a2, bf[cb][2], acc);
                    acc = MFMA16(a3, bf[cb][3], acc);
                    float s = 0.f;
                    #pragma unroll
                    for (int v = 0; v < 4; ++v)
                        if (g4 * 4 + v < cntc) s += silu_f(acc[v]);
                    if (cb == 0) tot0 += s;
                    else if (cb == 1) tot1 += s;
                    else if (cb == 2) tot2 += s;
                    else tot3 += s;
                }
                if (np < ke) { a0 = na0; a1 = na1; a2 = na2; a3 = na3; }
            }
        }

        // reduce across the 4 row-groups (g4)
        tot0 += __shfl_xor(tot0, 16, 64); tot0 += __shfl_xor(tot0, 32, 64);
        tot1 += __shfl_xor(tot1, 16, 64); tot1 += __shfl_xor(tot1, 32, 64);
        tot2 += __shfl_xor(tot2, 16, 64); tot2 += __shfl_xor(tot2, 32, 64);
        tot3 += __shfl_xor(tot3, 16, 64); tot3 += __shfl_xor(tot3, 32, 64);

        float t0 = __shfl(tot0, lane & 15, 64);
        float t1 = __shfl(tot1, lane & 15, 64);
        float t2 = __shfl(tot2, lane & 15, 64);
        float t3 = __shfl(tot3, lane & 15, 64);
        float outv = (lane < 16) ? t0 : (lane < 32) ? t1 : (lane < 48) ? t2 : t3;
        S[(size_t)n * 64 + lane] = outv;
    }
}

// ---------- node kernel: aggr=(S/deg)@W2+b2, update MLP, residual, LN ----------
#define NK_TILES 3125
#define NK_TPW 2
#define NK_BLOCKS 391   // ceil(3125 / (4 waves * 2 tiles))

__global__ __launch_bounds__(256, 2)
void k_node(const f16* __restrict__ h16, const float* __restrict__ h32,
            const float* __restrict__ S, const int* __restrict__ rowptr,
            const f16* __restrict__ w2t, const float* __restrict__ b2,
            const f16* __restrict__ u1t, const float* __restrict__ b1u,
            const f16* __restrict__ u2t, const float* __restrict__ b2u,
            const float* __restrict__ lng, const float* __restrict__ lnb,
            float* __restrict__ h32o, f16* __restrict__ h16o) {
    __shared__ f16 u1s[64 * 128];
    __shared__ f16 w2s[64 * 64], u2s[64 * 64];
    __shared__ float b2s[64], b1us[64], b2us[64], lngs[64], lnbs[64];
    __shared__ f16 trs[4][16 * 64];

    int tid = threadIdx.x;
    for (int i = tid; i < 8192; i += 256) {
        int c = i >> 7, k = i & 127;
        u1s[(c << 7) | (k ^ ((c & 7) << 3))] = u1t[i];
    }
    for (int i = tid; i < 4096; i += 256) {
        int c = i >> 6, k = i & 63;
        int p = (c << 6) | (k ^ ((c & 7) << 3));
        w2s[p] = w2t[i];
        u2s[p] = u2t[i];
    }
    if (tid < 64) {
        b2s[tid] = b2[tid]; b1us[tid] = b1u[tid]; b2us[tid] = b2u[tid];
        lngs[tid] = lng[tid]; lnbs[tid] = lnb[tid];
    }
    __syncthreads();

    int w = tid >> 6, lane = tid & 63;
    int row = lane & 15, g4 = lane >> 4;
    f16* tp = trs[w];

    #pragma unroll 1
    for (int t = 0; t < NK_TPW; ++t) {
        int tile = (blockIdx.x * 4 + w) * NK_TPW + t;
        if (tile >= NK_TILES) continue;
        int n0 = tile * 16;
        int nA = n0 + row;

        // ---- aggr = (S/deg) @ W2 + b2*(deg>0) ----
        int degA = rowptr[nA + 1] - rowptr[nA];
        float rdA = __builtin_amdgcn_rcpf((float)(degA > 0 ? degA : 1));
        const float* Srow = S + (size_t)nA * 64;
        f16x8 sa0, sa1;
        #pragma unroll
        for (int j = 0; j < 8; ++j) {
            sa0[j] = (f16)(Srow[g4 * 8 + j] * rdA);
            sa1[j] = (f16)(Srow[32 + g4 * 8 + j] * rdA);
        }
        int nC = n0 + g4 * 4;
        int r0 = rowptr[nC], r1 = rowptr[nC + 1], r2 = rowptr[nC + 2],
            r3 = rowptr[nC + 3], r4 = rowptr[nC + 4];
        float f0 = r1 > r0 ? 1.f : 0.f;
        float f1 = r2 > r1 ? 1.f : 0.f;
        float f2 = r3 > r2 ? 1.f : 0.f;
        float f3 = r4 > r3 ? 1.f : 0.f;

        f32x4 agg[4];
        #pragma unroll
        for (int cb = 0; cb < 4; ++cb) {
            int c = row + 16 * cb;
            float bv = b2s[c];
            agg[cb] = (f32x4){bv * f0, bv * f1, bv * f2, bv * f3};
            f16x8 wb0 = *(const f16x8*)&w2s[(c << 6) | ((g4 * 8) ^ ((c & 7) << 3))];
            f16x8 wb1 = *(const f16x8*)&w2s[(c << 6) | ((32 + g4 * 8) ^ ((c & 7) << 3))];
            agg[cb] = MFMA16(sa0, wb0, agg[cb]);
            agg[cb] = MFMA16(sa1, wb1, agg[cb]);
        }

        // ---- transpose aggr (C-frag) -> A-frag via wave-private LDS ----
        #pragma unroll
        for (int cb = 0; cb < 4; ++cb) {
            int c = row + 16 * cb;
            #pragma unroll
            for (int v = 0; v < 4; ++v) {
                int r = g4 * 4 + v;
                tp[(r << 6) | (c ^ ((r & 7) << 3))] = (f16)agg[cb][v];
            }
        }
        f16x8 ha0 = *(const f16x8*)&h16[(size_t)nA * 64 + g4 * 8];
        f16x8 ha1 = *(const f16x8*)&h16[(size_t)nA * 64 + 32 + g4 * 8];
        f16x8 aa2 = *(const f16x8*)&tp[(row << 6) | ((g4 * 8) ^ ((row & 7) << 3))];
        f16x8 aa3 = *(const f16x8*)&tp[(row << 6) | ((32 + g4 * 8) ^ ((row & 7) << 3))];

        // ---- hid = silu(cat[h, aggr] @ U1 + b1u) ----
        f32x4 hid[4];
        #pragma unroll
        for (int cb = 0; cb < 4; ++cb) {
            int c = row + 16 * cb;
            float bv = b1us[c];
            hid[cb] = (f32x4){bv, bv, bv, bv};
            hid[cb] = MFMA16(ha0, *(const f16x8*)&u1s[(c << 7) | ((g4 * 8) ^ ((c & 7) << 3))], hid[cb]);
            hid[cb] = MFMA16(ha1, *(const f16x8*)&u1s[(c << 7) | ((32 + g4 * 8) ^ ((c & 7) << 3))], hid[cb]);
            hid[cb] = MFMA16(aa2, *(const f16x8*)&u1s[(c << 7) | ((64 + g4 * 8) ^ ((c & 7) << 3))], hid[cb]);
            hid[cb] = MFMA16(aa3, *(const f16x8*)&u1s[(c << 7) | ((96 + g4 * 8) ^ ((c & 7) << 3))], hid[cb]);
        }

        // silu -> LDS (reuse tp, wave-private; lgkmcnt ordering handled by compiler)
        #pragma unroll
        for (int cb = 0; cb < 4; ++cb) {
            int c = row + 16 * cb;
            #pragma unroll
            for (int v = 0; v < 4; ++v) {
                int r = g4 * 4 + v;
                tp[(r << 6) | (c ^ ((r & 7) << 3))] = (f16)silu_f(hid[cb][v]);
            }
        }
        f16x8 za0 = *(const f16x8*)&tp[(row << 6) | ((g4 * 8) ^ ((row & 7) << 3))];
        f16x8 za1 = *(const f16x8*)&tp[(row << 6) | ((32 + g4 * 8) ^ ((row & 7) << 3))];

        f32x4 out[4];
        #pragma unroll
        for (int cb = 0; cb < 4; ++cb) {
            int c = row + 16 * cb;
            float bv = b2us[c];
            out[cb] = (f32x4){bv, bv, bv, bv};
            out[cb] = MFMA16(za0, *(const f16x8*)&u2s[(c << 6) | ((g4 * 8) ^ ((c & 7) << 3))], out[cb]);
            out[cb] = MFMA16(za1, *(const f16x8*)&u2s[(c << 6) | ((32 + g4 * 8) ^ ((c & 7) << 3))], out[cb]);
        }

        // ---- residual + LayerNorm ----
        #pragma unroll
        for (int v = 0; v < 4; ++v) {
            int n = nC + v;
            float hp[4];
            float s = 0.f, q = 0.f;
            #pragma unroll
            for (int cb = 0; cb < 4; ++cb) {
                float xv = h32[(size_t)n * 64 + row + 16 * cb] + out[cb][v];
                hp[cb] = xv; s += xv; q += xv * xv;
            }
            #pragma unroll
            for (int off = 1; off < 16; off <<= 1) {
                s += __shfl_xor(s, off, 64);
                q += __shfl_xor(q, off, 64);
            }
            float mu = s * 0.015625f;
            float var = q * 0.015625f - mu * mu;
            float rstd = __builtin_amdgcn_rsqf(var + EPSF);
            #pragma unroll
            for (int cb = 0; cb < 4; ++cb) {
                int c = row + 16 * cb;
                float o = (hp[cb] - mu) * rstd * lngs[c] + lnbs[c];
                h32o[(size_t)n * 64 + c] = o;
                h16o[(size_t)n * 64 + c] = (f16)o;
            }
        }
    }
}

extern "C" void kernel_launch(void* const* d_in, const int* in_sizes, int n_in,
                              void* d_out, int out_size, void* d_ws, size_t ws_size,
                              hipStream_t stream) {
    const float* x   = (const float*)d_in[0];
    const int*   ei  = (const int*)d_in[1];
    const float* ea  = (const float*)d_in[2];
    const float* nW  = (const float*)d_in[3];
    const float* nb  = (const float*)d_in[4];
    const float* eW  = (const float*)d_in[5];
    const float* eb  = (const float*)d_in[6];
    const float* mW1 = (const float*)d_in[7];
    const float* mb1 = (const float*)d_in[8];
    const float* mW2 = (const float*)d_in[9];
    const float* mb2 = (const float*)d_in[10];
    const float* uW1 = (const float*)d_in[11];
    const float* ub1 = (const float*)d_in[12];
    const float* uW2 = (const float*)d_in[13];
    const float* ub2 = (const float*)d_in[14];
    const float* lng = (const float*)d_in[15];
    const float* lnb = (const float*)d_in[16];

    char* p = (char*)d_ws;
    float* S    = (float*)p;  p += (size_t)NN * 64 * 4;
    float* h32  = (float*)p;  p += (size_t)NN * 64 * 4;
    f16*   h16  = (f16*)p;    p += (size_t)NN * 64 * 2;
    int*   rowptr = (int*)p;  p += (size_t)(NN + 1) * 4;
    int*   cursor = (int*)p;  p += (size_t)NN * 4;
    int*   cnt    = (int*)p;  p += (size_t)NN * 4;
    int*   esrc   = (int*)p;  p += (size_t)NE * 4;
    float* eavs   = (float*)p; p += (size_t)NE * 4;
    f16*   w1t = (f16*)p;    p += (size_t)DEPTH * 8192 * 2;
    f16*   w2t = (f16*)p;    p += (size_t)DEPTH * 4096 * 2;
    f16*   u1t = (f16*)p;    p += (size_t)DEPTH * 8192 * 2;
    f16*   u2t = (f16*)p;    p += (size_t)DEPTH * 4096 * 2;
    f16*   e16 = (f16*)p;    // optional, NE*64*2 = 102.4 MB
    size_t base_need = (size_t)(p - (char*)d_ws);
    bool use_e16 = ws_size >= base_need + (size_t)NE * 64 * 2;

    k_wt<<<(DEPTH * 8192 + 255) / 256, 256, 0, stream>>>(mW1, w1t, 128, 64, DEPTH * 8192);
    k_wt<<<(DEPTH * 4096 + 255) / 256, 256, 0, stream>>>(mW2, w2t, 64, 64, DEPTH * 4096);
    k_wt<<<(DEPTH * 8192 + 255) / 256, 256, 0, stream>>>(uW1, u1t, 128, 64, DEPTH * 8192);
    k_wt<<<(DEPTH * 4096 + 255) / 256, 256, 0, stream>>>(uW2, u2t, 64, 64, DEPTH * 4096);
    k_init_h<<<(NN * 64 + 255) / 256, 256, 0, stream>>>(x, nW, nb, h32, h16);

    hipMemsetAsync(cnt, 0, (size_t)NN * 4, stream);
    k_deg<<<(NE + 255) / 256, 256, 0, stream>>>(ei, cnt);
    k_scan<<<1, 1024, 0, stream>>>(cnt, rowptr, cursor);
    k_scatter<<<(NE + 255) / 256, 256, 0, stream>>>(ei, ea, cursor, esrc, eavs);
    if (use_e16)
        k_e16<<<(NE * 64 + 255) / 256, 256, 0, stream>>>(eavs, eW, eb, e16);

    for (int l = 0; l < DEPTH; ++l) {
        if (use_e16)
            k_edge<true><<<EK_BLOCKS, 512, 0, stream>>>(rowptr, esrc, eavs, e16, h16,
                w1t + (size_t)l * 8192, mb1 + l * 64, eW, eb, S);
        else
            k_edge<false><<<EK_BLOCKS, 512, 0, stream>>>(rowptr, esrc, eavs, e16, h16,
                w1t + (size_t)l * 8192, mb1 + l * 64, eW, eb, S);
        k_node<<<NK_BLOCKS, 256, 0, stream>>>(h16, h32, S, rowptr,
            w2t + (size_t)l * 4096, mb2 + l * 64,
            u1t + (size_t)l * 8192, ub1 + l * 64,
            u2t + (size_t)l * 4096, ub2 + l * 64,
            lng + l * 64, lnb + l * 64,
            (l == DEPTH - 1) ? (float*)d_out : h32, h16);
    }
}